// Round 2
// baseline (333.751 us; speedup 1.0000x reference)
//
#include <hip/hip_runtime.h>
#include <math.h>

// CEpsilonLoss: out = -mean(V) + mean_i( log( mean_j exp((V[j] - c[i,j]) * eps) ) ) / eps
// c[i,j] = sum_d |A[i,d] - B[j,d]|,  A=real [N,1024], B=fake [M,1024], eps=0.1
//
// exp args are ~ -115 => f32 underflow. We compute the row log-mean-exp STABLY
// (max-subtracted, flash-style partials) so the output is the finite f64-style
// value (~ -1152.9) instead of -inf.
//
// Kernel 1: tiled L1-distance (FP32 VALU — |a-b| is not bilinear, no MFMA),
//           fused epilogue: per-row block-local max + sum(exp(x - max)).
// Kernel 2: per-row combine of block partials -> lrow[i] (stable LSE).
// Kernel 3: deterministic tree reduction to the scalar.

#define D_DIM 1024
#define BI 128   // rows (real) per block
#define BJ 64    // cols (fake) per block
#define BK 32    // k-tile
#define TI 8     // per-thread rows
#define TJ 4     // per-thread cols

__global__ __launch_bounds__(256, 2)
void ceps_cdist_partial(const float* __restrict__ A,
                        const float* __restrict__ B,
                        const float* __restrict__ V,
                        float* __restrict__ pmax,   // [N][M/BJ]
                        float* __restrict__ psums,  // [N][M/BJ]
                        int N, int M)
{
    // k-major LDS tiles so fragment reads are contiguous ds_read_b128
    __shared__ float As[BK][BI];   // 16 KB
    __shared__ float Bs[BK][BJ];   //  8 KB

    const int t  = threadIdx.x;
    const int tx = t & 15;        // j group: cols tx*4 .. tx*4+3
    const int ty = t >> 4;        // i group: rows ty*8 .. ty*8+7
    const int jb = blockIdx.x;
    const int ib = blockIdx.y;
    const int i0 = ib * BI;
    const int j0 = jb * BJ;
    const int MB = M / BJ;

    // staging: each thread stages a 4x4 block (rows x k) with in-register transpose
    const int a_i = (t >> 3) << 2;          // 0..124
    const int a_k = (t & 7) << 2;           // 0..28
    const int b_j = ((t & 127) >> 3) << 2;  // 0..60 (threads < 128)

    float acc[TI][TJ];
    #pragma unroll
    for (int r = 0; r < TI; ++r)
        #pragma unroll
        for (int s = 0; s < TJ; ++s) acc[r][s] = 0.0f;

    for (int kt = 0; kt < D_DIM; kt += BK) {
        __syncthreads();
        {
            const float* Ab = &A[(i0 + a_i) * D_DIM + kt + a_k];
            float4 r0 = *(const float4*)(Ab);
            float4 r1 = *(const float4*)(Ab + D_DIM);
            float4 r2 = *(const float4*)(Ab + 2 * D_DIM);
            float4 r3 = *(const float4*)(Ab + 3 * D_DIM);
            *(float4*)&As[a_k + 0][a_i] = make_float4(r0.x, r1.x, r2.x, r3.x);
            *(float4*)&As[a_k + 1][a_i] = make_float4(r0.y, r1.y, r2.y, r3.y);
            *(float4*)&As[a_k + 2][a_i] = make_float4(r0.z, r1.z, r2.z, r3.z);
            *(float4*)&As[a_k + 3][a_i] = make_float4(r0.w, r1.w, r2.w, r3.w);
        }
        if (t < 128) {
            const float* Bb = &B[(j0 + b_j) * D_DIM + kt + a_k];
            float4 r0 = *(const float4*)(Bb);
            float4 r1 = *(const float4*)(Bb + D_DIM);
            float4 r2 = *(const float4*)(Bb + 2 * D_DIM);
            float4 r3 = *(const float4*)(Bb + 3 * D_DIM);
            *(float4*)&Bs[a_k + 0][b_j] = make_float4(r0.x, r1.x, r2.x, r3.x);
            *(float4*)&Bs[a_k + 1][b_j] = make_float4(r0.y, r1.y, r2.y, r3.y);
            *(float4*)&Bs[a_k + 2][b_j] = make_float4(r0.z, r1.z, r2.z, r3.z);
            *(float4*)&Bs[a_k + 3][b_j] = make_float4(r0.w, r1.w, r2.w, r3.w);
        }
        __syncthreads();

        #pragma unroll 8
        for (int kk = 0; kk < BK; ++kk) {
            float4 a0 = *(const float4*)&As[kk][ty * TI];
            float4 a1 = *(const float4*)&As[kk][ty * TI + 4];
            float4 b0 = *(const float4*)&Bs[kk][tx * TJ];
            float av[TI] = {a0.x, a0.y, a0.z, a0.w, a1.x, a1.y, a1.z, a1.w};
            float bv[TJ] = {b0.x, b0.y, b0.z, b0.w};
            #pragma unroll
            for (int r = 0; r < TI; ++r)
                #pragma unroll
                for (int s = 0; s < TJ; ++s)
                    acc[r][s] += fabsf(av[r] - bv[s]);
        }
    }

    // epilogue: x = (V[j] - c) * eps; per-row block max, then sum(exp(x - max))
    const float eps = 0.1f;
    float vj[TJ];
    #pragma unroll
    for (int s = 0; s < TJ; ++s) vj[s] = V[j0 + tx * TJ + s];

    #pragma unroll
    for (int r = 0; r < TI; ++r) {
        float x[TJ];
        #pragma unroll
        for (int s = 0; s < TJ; ++s) x[s] = (vj[s] - acc[r][s]) * eps;

        // block-local row max over 64 columns (4 per thread x 16 j-lanes)
        float m = fmaxf(fmaxf(x[0], x[1]), fmaxf(x[2], x[3]));
        m = fmaxf(m, __shfl_xor(m, 1));
        m = fmaxf(m, __shfl_xor(m, 2));
        m = fmaxf(m, __shfl_xor(m, 4));
        m = fmaxf(m, __shfl_xor(m, 8));

        float p = 0.0f;
        #pragma unroll
        for (int s = 0; s < TJ; ++s) p += expf(x[s] - m);
        p += __shfl_xor(p, 1);
        p += __shfl_xor(p, 2);
        p += __shfl_xor(p, 4);
        p += __shfl_xor(p, 8);

        if (tx == 0) {
            const int row = i0 + ty * TI + r;
            pmax [row * MB + jb] = m;
            psums[row * MB + jb] = p;
        }
    }
}

__global__ void ceps_row_logmean(const float* __restrict__ pmax,
                                 const float* __restrict__ psums,
                                 float* __restrict__ lrow,
                                 int N, int M)
{
    const int MB = M / BJ;
    int i = blockIdx.x * blockDim.x + threadIdx.x;
    if (i < N) {
        float m = -INFINITY;
        for (int jb = 0; jb < MB; ++jb) m = fmaxf(m, pmax[i * MB + jb]);
        float s = 0.0f;
        for (int jb = 0; jb < MB; ++jb)
            s += psums[i * MB + jb] * expf(pmax[i * MB + jb] - m);
        // log( (1/M) * sum_j exp(x_j) ) = m + log(s) - log(M)
        lrow[i] = m + logf(s) - logf((float)M);
    }
}

__global__ void ceps_final(const float* __restrict__ lrow,
                           const float* __restrict__ V,
                           float* __restrict__ out,
                           int N, int M)
{
    __shared__ float sl[256];
    __shared__ float sv[256];
    int t = threadIdx.x;
    float a = 0.0f, b = 0.0f;
    for (int i = t; i < N; i += 256) a += lrow[i];
    for (int i = t; i < M; i += 256) b += V[i];
    sl[t] = a; sv[t] = b;
    __syncthreads();
    for (int o = 128; o > 0; o >>= 1) {
        if (t < o) { sl[t] += sl[t + o]; sv[t] += sv[t + o]; }
        __syncthreads();
    }
    if (t == 0) {
        float fake_term = sv[0] / (float)M;
        float mean_log  = sl[0] / (float)N;
        out[0] = -fake_term + mean_log / 0.1f;
    }
}

extern "C" void kernel_launch(void* const* d_in, const int* in_sizes, int n_in,
                              void* d_out, int out_size, void* d_ws, size_t ws_size,
                              hipStream_t stream) {
    const float* A = (const float*)d_in[0];   // real_objects [N,1024]
    const float* B = (const float*)d_in[1];   // fake_objects [M,1024]
    const float* V = (const float*)d_in[2];   // fake_validity [M]

    const int N = in_sizes[0] / D_DIM;   // 2048
    const int M = in_sizes[1] / D_DIM;   // 2048
    const int MB = M / BJ;               // 32

    float* pmax  = (float*)d_ws;                      // N*MB floats
    float* psums = pmax + (size_t)N * MB;             // N*MB floats
    float* lrow  = psums + (size_t)N * MB;            // N floats

    dim3 grid(M / BJ, N / BI);                        // (32, 16) = 512 blocks
    ceps_cdist_partial<<<grid, 256, 0, stream>>>(A, B, V, pmax, psums, N, M);
    ceps_row_logmean<<<(N + 255) / 256, 256, 0, stream>>>(pmax, psums, lrow, N, M);
    ceps_final<<<1, 256, 0, stream>>>(lrow, V, (float*)d_out, N, M);
}